// Round 13
// baseline (515.796 us; speedup 1.0000x reference)
//
#include <hip/hip_runtime.h>
#include <math.h>

#define HD 128   // hidden dim
#define NG 256   // num graphs
#define NC 10    // classes
#define PCH 8    // pool chunks per graph
#define NXCD 8   // XCDs on MI355X
#define CHK 16   // features per chunk; fp16 -> 32 B per node-chunk row

typedef _Float16 f16x8 __attribute__((ext_vector_type(8)));   // 16 B
typedef float f32x4 __attribute__((ext_vector_type(4)));

// BATCHED layout: both sides share one node space [0, NT), side2 rows at +N1.
// Chunked fp16 activations: zc[((size_t)c * NT + n) * CHK + w]; per-XCD slice = NT*32B = 3.2MB < 4MB L2.
// csr_src stores LOCAL u16 indices; gather adds side base (edge endpoints share a side).
// Edges are pre-binned into 8 per-XCD-range partition lists so hist/fill stream only
// their own 1.65MB region (vs 8x26MB filtered scans) -> csr lines stay L2-resident.

// ---------------- edge partition (binning) ----------------

// entry: (dstoff << 16) | src_local;  dstoff = d - lo(r) < 12500 (14 bits), src_local < 65536.
__global__ __launch_bounds__(256) void part_x(const int* __restrict__ src1,
                                              const int* __restrict__ dst1, int E1,
                                              const int* __restrict__ src2,
                                              const int* __restrict__ dst2, int E2,
                                              int N1, int NT, int cap,
                                              int* __restrict__ pcnt,
                                              unsigned* __restrict__ pbuf) {
    __shared__ int lcnt[NXCD];
    __shared__ int lbase[NXCD];
    int ET = E1 + E2;
    for (int base = blockIdx.x * 2048; base < ET; base += gridDim.x * 2048) {
        if (threadIdx.x < NXCD) lcnt[threadIdx.x] = 0;
        __syncthreads();
        int pd[8]; unsigned ent[8]; bool val[8];
#pragma unroll
        for (int i = 0; i < 8; ++i) {
            int e = base + i * 256 + threadIdx.x;
            val[i] = e < ET;
            pd[i] = 0; ent[i] = 0;
            if (val[i]) {
                int dd, ss;
                if (e < E1) { dd = dst1[e]; ss = src1[e]; }
                else { dd = dst2[e - E1] + N1; ss = src2[e - E1]; }
                int p = (int)(((long long)dd << 3) / NT);
                int lo = (int)(((long long)NT * p + 7) >> 3);
                pd[i] = p;
                ent[i] = ((unsigned)(dd - lo) << 16) | (unsigned)ss;
                atomicAdd(&lcnt[p], 1);
            }
        }
        __syncthreads();
        if (threadIdx.x < NXCD) {
            lbase[threadIdx.x] = atomicAdd(&pcnt[threadIdx.x], lcnt[threadIdx.x]);
            lcnt[threadIdx.x] = 0;
        }
        __syncthreads();
#pragma unroll
        for (int i = 0; i < 8; ++i) {
            if (val[i]) {
                int slot = lbase[pd[i]] + atomicAdd(&lcnt[pd[i]], 1);
                pbuf[(size_t)pd[i] * cap + slot] = ent[i];
            }
        }
        __syncthreads();
    }
}

// ---------------- CSR build from partitions ----------------

__global__ __launch_bounds__(256) void hist_p(const unsigned* __restrict__ pbuf,
                                              const int* __restrict__ pcnt, int cap, int NT,
                                              int* __restrict__ deg) {
    int r = blockIdx.x & (NXCD - 1);
    int lo = (int)(((long long)NT * r + 7) >> 3);
    int cnt = pcnt[r];
    const unsigned* buf = pbuf + (size_t)r * cap;
    int nb = gridDim.x >> 3, cb = blockIdx.x >> 3;
    for (int i = cb * 256 + threadIdx.x; i < cnt; i += nb * 256)
        atomicAdd(&deg[lo + (int)(buf[i] >> 16)], 1);
}

__global__ __launch_bounds__(256) void fill_p(const unsigned* __restrict__ pbuf,
                                              const int* __restrict__ pcnt, int cap, int NT,
                                              int* __restrict__ cursor,
                                              unsigned short* __restrict__ csr_src) {
    int r = blockIdx.x & (NXCD - 1);
    int lo = (int)(((long long)NT * r + 7) >> 3);
    int cnt = pcnt[r];
    const unsigned* buf = pbuf + (size_t)r * cap;
    int nb = gridDim.x >> 3, cb = blockIdx.x >> 3;
    for (int i = cb * 256 + threadIdx.x; i < cnt; i += nb * 256) {
        unsigned u = buf[i];
        int d = lo + (int)(u >> 16);
        int pos = atomicAdd(&cursor[d], 1);
        csr_src[pos] = (unsigned short)(u & 0xFFFFu);
    }
}

__global__ void block_sum(const int* __restrict__ deg, int N, int* __restrict__ bsum) {
    __shared__ int sh[256];
    int i = blockIdx.x * 256 + threadIdx.x;
    sh[threadIdx.x] = (i < N) ? deg[i] : 0;
    __syncthreads();
    for (int s = 128; s > 0; s >>= 1) {
        if (threadIdx.x < s) sh[threadIdx.x] += sh[threadIdx.x + s];
        __syncthreads();
    }
    if (threadIdx.x == 0) bsum[blockIdx.x] = sh[0];
}

// parallel exclusive scan of block sums (nb <= 512)
__global__ void scan_bsum(int* __restrict__ bsum, int nb) {
    __shared__ int sh[512];
    int t = threadIdx.x;
    int v = (t < nb) ? bsum[t] : 0;
    sh[t] = v;
    __syncthreads();
    for (int s = 1; s < 512; s <<= 1) {
        int tv = 0;
        if (t >= s) tv = sh[t - s];
        __syncthreads();
        sh[t] += tv;
        __syncthreads();
    }
    if (t < nb) bsum[t] = sh[t] - v;   // exclusive
}

__global__ void scan_write(const int* __restrict__ deg, const int* __restrict__ bsum,
                           int N, int E, int* __restrict__ off, int* __restrict__ cursor,
                           float* __restrict__ dinv) {
    __shared__ int sh[256];
    int i = blockIdx.x * 256 + threadIdx.x;
    int v = (i < N) ? deg[i] : 0;
    sh[threadIdx.x] = v;
    __syncthreads();
    for (int s = 1; s < 256; s <<= 1) {
        int t = 0;
        if (threadIdx.x >= s) t = sh[threadIdx.x - s];
        __syncthreads();
        if (threadIdx.x >= s) sh[threadIdx.x] += t;
        __syncthreads();
    }
    if (i < N) {
        int excl = sh[threadIdx.x] - v + bsum[blockIdx.x];
        off[i] = excl;
        cursor[i] = excl;
        dinv[i] = rsqrtf((float)v + 1.0f);
        if (i == N - 1) off[N] = E;
    }
}

// both sides: blockIdx.x = side
__global__ void bounds_kernel(const int* __restrict__ batch1, const int* __restrict__ batch2,
                              int N, int* __restrict__ bnd, float* __restrict__ cnt) {
    int side = blockIdx.x;
    const int* batch = side ? batch2 : batch1;
    int* bn = bnd + side * (NG + 1);
    float* cn = cnt + side * NG;
    int g = threadIdx.x;
    int lo = 0, hi = N;
    while (lo < hi) { int mid = (lo + hi) >> 1; if (batch[mid] < g) lo = mid + 1; else hi = mid; }
    bn[g] = lo;
    if (g == 0) bn[NG] = N;
    int lo2 = lo, hi2 = N, v = g + 1;
    while (lo2 < hi2) { int mid = (lo2 + hi2) >> 1; if (batch[mid] < v) lo2 = mid + 1; else hi2 = mid; }
    cn[g] = (float)(lo2 - lo);
}

// ---------------- fp16 conversion (batched) ----------------

// unified chunked x: side1 [N1][128] -> chunks 0..7; side2 [N2][64] -> chunks 0..3, 4..7 zero.
__global__ __launch_bounds__(256) void xcvt_all(const float* __restrict__ x1,
                                                const float* __restrict__ x2,
                                                _Float16* __restrict__ xc, int N1, int NT) {
    int i = blockIdx.x * 256 + threadIdx.x;
    if (i >= NT * 16) return;
    int n = i >> 4, o = i & 15;
    f16x8 v = {0, 0, 0, 0, 0, 0, 0, 0};
    if (n < N1) {
        const float4 u0 = *(const float4*)(x1 + (size_t)n * 128 + o * 8);
        const float4 u1 = *(const float4*)(x1 + (size_t)n * 128 + o * 8 + 4);
        v[0] = (_Float16)u0.x; v[1] = (_Float16)u0.y; v[2] = (_Float16)u0.z; v[3] = (_Float16)u0.w;
        v[4] = (_Float16)u1.x; v[5] = (_Float16)u1.y; v[6] = (_Float16)u1.z; v[7] = (_Float16)u1.w;
    } else if (o < 8) {
        const float4 u0 = *(const float4*)(x2 + (size_t)(n - N1) * 64 + o * 8);
        const float4 u1 = *(const float4*)(x2 + (size_t)(n - N1) * 64 + o * 8 + 4);
        v[0] = (_Float16)u0.x; v[1] = (_Float16)u0.y; v[2] = (_Float16)u0.z; v[3] = (_Float16)u0.w;
        v[4] = (_Float16)u1.x; v[5] = (_Float16)u1.y; v[6] = (_Float16)u1.z; v[7] = (_Float16)u1.w;
    }
    *(f16x8*)(xc + ((size_t)(o >> 1) * NT + n) * CHK + ((o & 1) << 3)) = v;
}

// 6 weight segments, each [128][128] j-major (K padded to 128):
// seg0=w1, seg1=w2(zero-pad k>=64), seg2/3=ws1 l0/l1, seg4/5=ws2 l0/l1
__global__ __launch_bounds__(256) void wcvt_all(const float* __restrict__ w1,
                                                const float* __restrict__ w2,
                                                const float* __restrict__ ws1,
                                                const float* __restrict__ ws2,
                                                _Float16* __restrict__ wt) {
    int i = blockIdx.x * 256 + threadIdx.x;
    if (i >= 6 * 16384) return;
    int seg = i >> 14;
    int r = i & 16383;
    int j = r >> 7, k = r & 127;
    float val = 0.f;
    switch (seg) {
        case 0: val = w1[k * 128 + j]; break;
        case 1: val = (k < 64) ? w2[k * 128 + j] : 0.f; break;
        case 2: val = ws1[k * 128 + j]; break;
        case 3: val = ws1[16384 + k * 128 + j]; break;
        case 4: val = ws2[k * 128 + j]; break;
        case 5: val = ws2[16384 + k * 128 + j]; break;
    }
    wt[i] = (_Float16)val;
}

// ---------------- conv (batched) ----------------

// MFMA matmul: z = dinv * (xc @ W), K=128 uniform; weight segment selected per tile side.
__global__ __launch_bounds__(256) void matmul_mfma(const _Float16* __restrict__ xc,
                                                   const _Float16* __restrict__ wt1,
                                                   const _Float16* __restrict__ wt2,
                                                   const float* __restrict__ dinv,
                                                   _Float16* __restrict__ outc,
                                                   int N1, int NT) {
    int wid = blockIdx.x * 4 + (threadIdx.x >> 6);
    int lane = threadIdx.x & 63;
    int row16 = lane & 15;
    int oct = lane >> 4;
    int ntiles = NT >> 4;
    if (wid >= ntiles) return;
    int n0 = wid << 4;
    int na = n0 + row16;
    const _Float16* wt = (n0 < N1) ? wt1 : wt2;

    f32x4 acc[8];
#pragma unroll
    for (int ob = 0; ob < 8; ++ob) acc[ob] = (f32x4){0.f, 0.f, 0.f, 0.f};

#pragma unroll
    for (int kb = 0; kb < 128; kb += 32) {
        int ka = kb + oct * 8;
        f16x8 a = *(const f16x8*)(xc + ((size_t)(ka >> 4) * NT + na) * CHK + (ka & (CHK - 1)));
#pragma unroll
        for (int ob = 0; ob < 8; ++ob) {
            int j = ob * 16 + row16;
            f16x8 b = *(const f16x8*)(wt + (size_t)j * 128 + ka);
            acc[ob] = __builtin_amdgcn_mfma_f32_16x16x32_f16(a, b, acc[ob], 0, 0, 0);
        }
    }

#pragma unroll
    for (int r = 0; r < 4; ++r) {
        int n = n0 + oct * 4 + r;
        float dn = dinv[n];
#pragma unroll
        for (int ob = 0; ob < 8; ++ob) {
            outc[((size_t)ob * NT + n) * CHK + row16] = (_Float16)(acc[ob][r] * dn);
        }
    }
}

// Chunk-resident gather, fp16, 4-phase predicated: 8 lanes/node = 2 half-row x 4 edge-phase.
__global__ __launch_bounds__(256) void gather_chunked(const int* __restrict__ off,
                                                      const unsigned short* __restrict__ csr_src,
                                                      const float* __restrict__ dinv,
                                                      const _Float16* __restrict__ zc,
                                                      const float* __restrict__ b1,
                                                      const float* __restrict__ b2,
                                                      _Float16* __restrict__ outc,
                                                      int N1, int NT) {
    const int c = blockIdx.x;                          // feature chunk = XCD
    const int n = blockIdx.y * 32 + (threadIdx.x >> 3);
    if (n >= NT) return;
    const int sub = threadIdx.x & 7;
    const int h8 = (sub & 1) << 3;                     // half-row: halves 0..7 or 8..15
    const int ph = sub >> 1;                           // edge phase 0..3
    const int sbase = (n < N1) ? 0 : N1;
    const _Float16* base = zc + ((size_t)c * NT + sbase) * CHK + h8;   // indexed by LOCAL s
    const int e0 = off[n], e1 = off[n + 1];
    const int deg = e1 - e0;
    const int cl = (deg > ph) ? ((deg - ph + 3) >> 2) : 0;   // edges this phase covers
    // hoist self row + bias + dinv above the edge loop
    const float dn = dinv[n];
    const f16x8 zs = *(const f16x8*)(base + (size_t)(n - sbase) * CHK);
    const float* bsel = (n < N1) ? b1 : b2;
    const float4 bb0 = *(const float4*)(bsel + c * CHK + h8);
    const float4 bb1 = *(const float4*)(bsel + c * CHK + h8 + 4);

    float a0 = 0.f, a1 = 0.f, a2 = 0.f, a3 = 0.f, a4 = 0.f, a5 = 0.f, a6 = 0.f, a7 = 0.f;
    for (int t = 0; t < cl; t += 8) {
        int slast = e1 - 1;   // valid whenever loop runs (cl>0 -> deg>0)
#pragma unroll
        for (int i = 0; i < 8; ++i) {
            int idx = t + i;
            int ee = e0 + ph + 4 * idx;
            bool valid = idx < cl;
            int epos = valid ? ee : slast;
            int s = csr_src[epos];
            f16x8 v = *(const f16x8*)(base + (size_t)s * CHK);
            float m = valid ? 1.f : 0.f;
            a0 += (float)v[0] * m; a1 += (float)v[1] * m;
            a2 += (float)v[2] * m; a3 += (float)v[3] * m;
            a4 += (float)v[4] * m; a5 += (float)v[5] * m;
            a6 += (float)v[6] * m; a7 += (float)v[7] * m;
        }
    }
    // reduce the 4 phases (lanes sub^2, sub^4 share the same half-row)
    a0 += __shfl_xor(a0, 2); a1 += __shfl_xor(a1, 2); a2 += __shfl_xor(a2, 2); a3 += __shfl_xor(a3, 2);
    a4 += __shfl_xor(a4, 2); a5 += __shfl_xor(a5, 2); a6 += __shfl_xor(a6, 2); a7 += __shfl_xor(a7, 2);
    a0 += __shfl_xor(a0, 4); a1 += __shfl_xor(a1, 4); a2 += __shfl_xor(a2, 4); a3 += __shfl_xor(a3, 4);
    a4 += __shfl_xor(a4, 4); a5 += __shfl_xor(a5, 4); a6 += __shfl_xor(a6, 4); a7 += __shfl_xor(a7, 4);
    if (ph == 0) {
        float o0 = (a0 + (float)zs[0]) * dn + bb0.x;
        float o1 = (a1 + (float)zs[1]) * dn + bb0.y;
        float o2 = (a2 + (float)zs[2]) * dn + bb0.z;
        float o3 = (a3 + (float)zs[3]) * dn + bb0.w;
        float o4 = (a4 + (float)zs[4]) * dn + bb1.x;
        float o5 = (a5 + (float)zs[5]) * dn + bb1.y;
        float o6 = (a6 + (float)zs[6]) * dn + bb1.z;
        float o7 = (a7 + (float)zs[7]) * dn + bb1.w;
        f16x8 o;
        o[0] = (_Float16)(o0 > 0.f ? o0 : 0.f);
        o[1] = (_Float16)(o1 > 0.f ? o1 : 0.f);
        o[2] = (_Float16)(o2 > 0.f ? o2 : 0.f);
        o[3] = (_Float16)(o3 > 0.f ? o3 : 0.f);
        o[4] = (_Float16)(o4 > 0.f ? o4 : 0.f);
        o[5] = (_Float16)(o5 > 0.f ? o5 : 0.f);
        o[6] = (_Float16)(o6 > 0.f ? o6 : 0.f);
        o[7] = (_Float16)(o7 > 0.f ? o7 : 0.f);
        *(f16x8*)(outc + ((size_t)c * NT + n) * CHK + h8) = o;
    }
}

// ---------------- pooling + head (batched) ----------------

__global__ void pool_kernel(const _Float16* __restrict__ h, const int* __restrict__ bnd,
                            float* __restrict__ part, int N1, int NT) {
    int g = blockIdx.x;
    int cch = blockIdx.y;
    int side = blockIdx.z;
    int j = threadIdx.x;   // HD threads
    const int* bn = bnd + side * (NG + 1);
    int nbase = side * N1;
    size_t fo = ((size_t)(j >> 4) * NT) * CHK + (j & (CHK - 1));
    int s = bn[g], e = bn[g + 1];
    float acc = 0.f;
    for (int n = s + cch; n < e; n += PCH) acc += (float)h[fo + (size_t)(nbase + n) * CHK];
    part[(((size_t)side * PCH + cch) * NG + g) * HD + j] = acc;
}

__global__ void lin_kernel(const float* __restrict__ part, const float* __restrict__ cnt,
                           const float* __restrict__ W1, const float* __restrict__ bl1,
                           const float* __restrict__ W2, const float* __restrict__ bl2,
                           float* __restrict__ out) {
    __shared__ float row[HD];
    int g = blockIdx.x, side = blockIdx.y, j = threadIdx.x;
    const float* W = side ? W2 : W1;
    const float* bl = side ? bl2 : bl1;
    float s0 = 0.f;
#pragma unroll
    for (int c = 0; c < PCH; ++c) s0 += part[(((size_t)side * PCH + c) * NG + g) * HD + j];
    float c = cnt[side * NG + g];
    c = c > 1.f ? c : 1.f;
    row[j] = s0 / c;
    __syncthreads();
    float s = bl[j];
#pragma unroll 8
    for (int k = 0; k < HD; ++k) s += row[k] * W[k * HD + j];
    out[(size_t)side * NG * HD + g * HD + j] = s > 0.f ? s : 0.f;
}

__global__ void final_kernel(const float* __restrict__ outg,
                             const float* __restrict__ W3, const float* __restrict__ b3,
                             float* __restrict__ out) {
    __shared__ float c[2 * HD];
    __shared__ float logit[NC];
    __shared__ float lse;
    int g = blockIdx.x, t = threadIdx.x;   // 256 threads
    c[t] = (t < HD) ? outg[g * HD + t] : outg[NG * HD + g * HD + (t - HD)];
    __syncthreads();
    if (t < NC) {
        float s = b3[t];
#pragma unroll 8
        for (int k = 0; k < 2 * HD; ++k) s += c[k] * W3[k * NC + t];
        logit[t] = s;
    }
    __syncthreads();
    if (t == 0) {
        float m = logit[0];
        for (int i = 1; i < NC; ++i) m = fmaxf(m, logit[i]);
        float s = 0.f;
        for (int i = 0; i < NC; ++i) s += expf(logit[i] - m);
        lse = m + logf(s);
    }
    __syncthreads();
    if (t < NC) out[2 * NG * HD + g * NC + t] = logit[t] - lse;
}

// ---------------- host side ----------------

extern "C" void kernel_launch(void* const* d_in, const int* in_sizes, int n_in,
                              void* d_out, int out_size, void* d_ws, size_t ws_size,
                              hipStream_t stream) {
    const float* x1  = (const float*)d_in[0];
    const int*   ei1 = (const int*)d_in[1];
    const int*   b1a = (const int*)d_in[2];
    const float* x2  = (const float*)d_in[3];
    const int*   ei2 = (const int*)d_in[4];
    const int*   b2a = (const int*)d_in[5];
    const float* conv1_w = (const float*)d_in[6];
    const float* conv1_b = (const float*)d_in[7];
    const float* convs1_w = (const float*)d_in[8];
    const float* convs1_b = (const float*)d_in[9];
    const float* conv2_w = (const float*)d_in[10];
    const float* conv2_b = (const float*)d_in[11];
    const float* convs2_w = (const float*)d_in[12];
    const float* convs2_b = (const float*)d_in[13];
    const float* lin1_w = (const float*)d_in[14];
    const float* lin1_b = (const float*)d_in[15];
    const float* lin2_w = (const float*)d_in[16];
    const float* lin2_b = (const float*)d_in[17];
    const float* lin3_w = (const float*)d_in[18];
    const float* lin3_b = (const float*)d_in[19];

    const int N1 = in_sizes[2];
    const int N2 = in_sizes[5];
    const int E1 = in_sizes[1] / 2;
    const int E2 = in_sizes[4] / 2;
    const int NT = N1 + N2;
    const int ET = E1 + E2;
    const int cap = ET / NXCD + 8192;   // per-partition capacity (binomial margin)

    const int* src1 = ei1;
    const int* dst1 = ei1 + E1;
    const int* src2 = ei2;
    const int* dst2 = ei2 + E2;

    char* ws = (char*)d_ws;
    size_t p = 0;
    auto alloc = [&](size_t bytes) { void* r = ws + p; p = (p + bytes + 255) & ~(size_t)255; return r; };
    _Float16* B0  = (_Float16*)alloc((size_t)NT * HD * sizeof(_Float16));
    _Float16* B1  = (_Float16*)alloc((size_t)NT * HD * sizeof(_Float16));
    _Float16* XC  = (_Float16*)alloc((size_t)NT * HD * sizeof(_Float16));
    _Float16* WT  = (_Float16*)alloc((size_t)6 * 16384 * sizeof(_Float16));
    float* dinv   = (float*)alloc((size_t)NT * sizeof(float));
    float* part   = (float*)alloc((size_t)2 * PCH * NG * HD * sizeof(float));
    float* cnt    = (float*)alloc((size_t)2 * NG * sizeof(float));
    int* deg      = (int*)alloc((size_t)NT * sizeof(int));
    int* off      = (int*)alloc((size_t)(NT + 1) * sizeof(int));
    int* cursor   = (int*)alloc((size_t)NT * sizeof(int));
    unsigned short* csr_src = (unsigned short*)alloc((size_t)ET * sizeof(unsigned short));
    int* bsum     = (int*)alloc(512 * sizeof(int));
    int* bnd      = (int*)alloc((size_t)2 * (NG + 1) * sizeof(int));
    int* pcnt     = (int*)alloc((size_t)NXCD * sizeof(int));
    unsigned* pbuf = (unsigned*)alloc((size_t)NXCD * cap * sizeof(unsigned));

    float* out = (float*)d_out;
    const int nb = (NT + 255) / 256;   // 391 <= 512

    // conversions
    wcvt_all<<<(6 * 16384 + 255) / 256, 256, 0, stream>>>(conv1_w, conv2_w, convs1_w, convs2_w, WT);
    xcvt_all<<<(NT * 16 + 255) / 256, 256, 0, stream>>>(x1, x2, XC, N1, NT);

    // edge binning + CSR build (both sides, one node space)
    hipMemsetAsync(pcnt, 0, NXCD * sizeof(int), stream);
    hipMemsetAsync(deg, 0, (size_t)NT * sizeof(int), stream);
    part_x<<<1024, 256, 0, stream>>>(src1, dst1, E1, src2, dst2, E2, N1, NT, cap, pcnt, pbuf);
    hist_p<<<2048, 256, 0, stream>>>(pbuf, pcnt, cap, NT, deg);
    block_sum<<<nb, 256, 0, stream>>>(deg, NT, bsum);
    scan_bsum<<<1, 512, 0, stream>>>(bsum, nb);
    scan_write<<<nb, 256, 0, stream>>>(deg, bsum, NT, ET, off, cursor, dinv);
    fill_p<<<2048, 256, 0, stream>>>(pbuf, pcnt, cap, NT, cursor, csr_src);
    bounds_kernel<<<2, NG, 0, stream>>>(b1a, b2a, N1, bnd, cnt);

    const int mm_blocks = ((NT >> 4) + 3) / 4;
    const dim3 ga_grid(NXCD, (NT + 31) / 32);

    for (int l = 0; l < 3; ++l) {
        const _Float16* in = (l == 0) ? XC : B1;
        const _Float16* wt1 = WT + ((l == 0) ? 0 : (size_t)(2 + (l - 1)) * 16384);
        const _Float16* wt2 = WT + ((l == 0) ? (size_t)16384 : (size_t)(4 + (l - 1)) * 16384);
        const float* bb1 = (l == 0) ? conv1_b : convs1_b + (size_t)(l - 1) * HD;
        const float* bb2 = (l == 0) ? conv2_b : convs2_b + (size_t)(l - 1) * HD;
        matmul_mfma<<<mm_blocks, 256, 0, stream>>>(in, wt1, wt2, dinv, B0, N1, NT);
        gather_chunked<<<ga_grid, 256, 0, stream>>>(off, csr_src, dinv, B0, bb1, bb2, B1, N1, NT);
    }

    pool_kernel<<<dim3(NG, PCH, 2), HD, 0, stream>>>(B1, bnd, part, N1, NT);
    lin_kernel<<<dim3(NG, 2), HD, 0, stream>>>(part, cnt, lin1_w, lin1_b, lin2_w, lin2_b, out);
    final_kernel<<<NG, 2 * HD, 0, stream>>>(out, lin3_w, lin3_b, out);
}

// Round 14
// 511.803 us; speedup vs baseline: 1.0078x; 1.0078x over previous
//
#include <hip/hip_runtime.h>
#include <math.h>

#define HD 128   // hidden dim
#define NG 256   // num graphs
#define NC 10    // classes
#define PCH 8    // pool chunks per graph
#define NXCD 8   // XCDs on MI355X
#define CHK 16   // features per chunk; fp16 -> 32 B per node-chunk row

typedef _Float16 f16x8 __attribute__((ext_vector_type(8)));   // 16 B
typedef float f32x4 __attribute__((ext_vector_type(4)));

// BATCHED layout: both sides share one node space [0, NT), side2 rows at +N1.
// Chunked fp16 activations: zc[((size_t)c * NT + n) * CHK + w]; per-XCD slice = NT*32B = 3.2MB < 4MB L2.
// csr_src stores LOCAL u16 indices; gather adds side base (edge endpoints share a side).
// Edges are pre-binned into 8 per-XCD-range partition lists so hist/fill stream only
// their own 1.65MB region -> csr lines stay L2-resident.

// ---------------- edge partition (binning) ----------------

// entry: (dstoff << 16) | src_local;  dstoff = d - lo(r) < 12500 (14 bits), src_local < 65536.
__global__ __launch_bounds__(256) void part_x(const int* __restrict__ src1,
                                              const int* __restrict__ dst1, int E1,
                                              const int* __restrict__ src2,
                                              const int* __restrict__ dst2, int E2,
                                              int N1, int NT, int cap,
                                              int* __restrict__ pcnt,
                                              unsigned* __restrict__ pbuf) {
    __shared__ int lcnt[NXCD];
    __shared__ int lbase[NXCD];
    int ET = E1 + E2;
    for (int base = blockIdx.x * 2048; base < ET; base += gridDim.x * 2048) {
        if (threadIdx.x < NXCD) lcnt[threadIdx.x] = 0;
        __syncthreads();
        int pd[8]; unsigned ent[8]; bool val[8];
#pragma unroll
        for (int i = 0; i < 8; ++i) {
            int e = base + i * 256 + threadIdx.x;
            val[i] = e < ET;
            pd[i] = 0; ent[i] = 0;
            if (val[i]) {
                int dd, ss;
                if (e < E1) { dd = dst1[e]; ss = src1[e]; }
                else { dd = dst2[e - E1] + N1; ss = src2[e - E1]; }
                int p = (int)(((long long)dd << 3) / NT);
                int lo = (int)(((long long)NT * p + 7) >> 3);
                pd[i] = p;
                ent[i] = ((unsigned)(dd - lo) << 16) | (unsigned)ss;
                atomicAdd(&lcnt[p], 1);
            }
        }
        __syncthreads();
        if (threadIdx.x < NXCD) {
            lbase[threadIdx.x] = atomicAdd(&pcnt[threadIdx.x], lcnt[threadIdx.x]);
            lcnt[threadIdx.x] = 0;
        }
        __syncthreads();
#pragma unroll
        for (int i = 0; i < 8; ++i) {
            if (val[i]) {
                int slot = lbase[pd[i]] + atomicAdd(&lcnt[pd[i]], 1);
                pbuf[(size_t)pd[i] * cap + slot] = ent[i];
            }
        }
        __syncthreads();
    }
}

// ---------------- CSR build from partitions ----------------

__global__ __launch_bounds__(256) void hist_p(const unsigned* __restrict__ pbuf,
                                              const int* __restrict__ pcnt, int cap, int NT,
                                              int* __restrict__ deg) {
    int r = blockIdx.x & (NXCD - 1);
    int lo = (int)(((long long)NT * r + 7) >> 3);
    int cnt = pcnt[r];
    const unsigned* buf = pbuf + (size_t)r * cap;
    int nb = gridDim.x >> 3, cb = blockIdx.x >> 3;
    for (int i = cb * 256 + threadIdx.x; i < cnt; i += nb * 256)
        atomicAdd(&deg[lo + (int)(buf[i] >> 16)], 1);
}

__global__ __launch_bounds__(256) void fill_p(const unsigned* __restrict__ pbuf,
                                              const int* __restrict__ pcnt, int cap, int NT,
                                              int* __restrict__ cursor,
                                              unsigned short* __restrict__ csr_src) {
    int r = blockIdx.x & (NXCD - 1);
    int lo = (int)(((long long)NT * r + 7) >> 3);
    int cnt = pcnt[r];
    const unsigned* buf = pbuf + (size_t)r * cap;
    int nb = gridDim.x >> 3, cb = blockIdx.x >> 3;
    for (int i = cb * 256 + threadIdx.x; i < cnt; i += nb * 256) {
        unsigned u = buf[i];
        int d = lo + (int)(u >> 16);
        int pos = atomicAdd(&cursor[d], 1);
        csr_src[pos] = (unsigned short)(u & 0xFFFFu);
    }
}

__global__ void block_sum(const int* __restrict__ deg, int N, int* __restrict__ bsum) {
    __shared__ int sh[256];
    int i = blockIdx.x * 256 + threadIdx.x;
    sh[threadIdx.x] = (i < N) ? deg[i] : 0;
    __syncthreads();
    for (int s = 128; s > 0; s >>= 1) {
        if (threadIdx.x < s) sh[threadIdx.x] += sh[threadIdx.x + s];
        __syncthreads();
    }
    if (threadIdx.x == 0) bsum[blockIdx.x] = sh[0];
}

// parallel exclusive scan of block sums (nb <= 512)
__global__ void scan_bsum(int* __restrict__ bsum, int nb) {
    __shared__ int sh[512];
    int t = threadIdx.x;
    int v = (t < nb) ? bsum[t] : 0;
    sh[t] = v;
    __syncthreads();
    for (int s = 1; s < 512; s <<= 1) {
        int tv = 0;
        if (t >= s) tv = sh[t - s];
        __syncthreads();
        sh[t] += tv;
        __syncthreads();
    }
    if (t < nb) bsum[t] = sh[t] - v;   // exclusive
}

__global__ void scan_write(const int* __restrict__ deg, const int* __restrict__ bsum,
                           int N, int E, int* __restrict__ off, int* __restrict__ cursor,
                           float* __restrict__ dinv) {
    __shared__ int sh[256];
    int i = blockIdx.x * 256 + threadIdx.x;
    int v = (i < N) ? deg[i] : 0;
    sh[threadIdx.x] = v;
    __syncthreads();
    for (int s = 1; s < 256; s <<= 1) {
        int t = 0;
        if (threadIdx.x >= s) t = sh[threadIdx.x - s];
        __syncthreads();
        if (threadIdx.x >= s) sh[threadIdx.x] += t;
        __syncthreads();
    }
    if (i < N) {
        int excl = sh[threadIdx.x] - v + bsum[blockIdx.x];
        off[i] = excl;
        cursor[i] = excl;
        dinv[i] = rsqrtf((float)v + 1.0f);
        if (i == N - 1) off[N] = E;
    }
}

// both sides: blockIdx.x = side
__global__ void bounds_kernel(const int* __restrict__ batch1, const int* __restrict__ batch2,
                              int N, int* __restrict__ bnd, float* __restrict__ cnt) {
    int side = blockIdx.x;
    const int* batch = side ? batch2 : batch1;
    int* bn = bnd + side * (NG + 1);
    float* cn = cnt + side * NG;
    int g = threadIdx.x;
    int lo = 0, hi = N;
    while (lo < hi) { int mid = (lo + hi) >> 1; if (batch[mid] < g) lo = mid + 1; else hi = mid; }
    bn[g] = lo;
    if (g == 0) bn[NG] = N;
    int lo2 = lo, hi2 = N, v = g + 1;
    while (lo2 < hi2) { int mid = (lo2 + hi2) >> 1; if (batch[mid] < v) lo2 = mid + 1; else hi2 = mid; }
    cn[g] = (float)(lo2 - lo);
}

// ---------------- fp16 conversion (batched) ----------------

// unified chunked x: side1 [N1][128] -> chunks 0..7; side2 [N2][64] -> chunks 0..3, 4..7 zero.
__global__ __launch_bounds__(256) void xcvt_all(const float* __restrict__ x1,
                                                const float* __restrict__ x2,
                                                _Float16* __restrict__ xc, int N1, int NT) {
    int i = blockIdx.x * 256 + threadIdx.x;
    if (i >= NT * 16) return;
    int n = i >> 4, o = i & 15;
    f16x8 v = {0, 0, 0, 0, 0, 0, 0, 0};
    if (n < N1) {
        const float4 u0 = *(const float4*)(x1 + (size_t)n * 128 + o * 8);
        const float4 u1 = *(const float4*)(x1 + (size_t)n * 128 + o * 8 + 4);
        v[0] = (_Float16)u0.x; v[1] = (_Float16)u0.y; v[2] = (_Float16)u0.z; v[3] = (_Float16)u0.w;
        v[4] = (_Float16)u1.x; v[5] = (_Float16)u1.y; v[6] = (_Float16)u1.z; v[7] = (_Float16)u1.w;
    } else if (o < 8) {
        const float4 u0 = *(const float4*)(x2 + (size_t)(n - N1) * 64 + o * 8);
        const float4 u1 = *(const float4*)(x2 + (size_t)(n - N1) * 64 + o * 8 + 4);
        v[0] = (_Float16)u0.x; v[1] = (_Float16)u0.y; v[2] = (_Float16)u0.z; v[3] = (_Float16)u0.w;
        v[4] = (_Float16)u1.x; v[5] = (_Float16)u1.y; v[6] = (_Float16)u1.z; v[7] = (_Float16)u1.w;
    }
    *(f16x8*)(xc + ((size_t)(o >> 1) * NT + n) * CHK + ((o & 1) << 3)) = v;
}

// 6 weight segments, each [128][128] j-major (K padded to 128):
// seg0=w1, seg1=w2(zero-pad k>=64), seg2/3=ws1 l0/l1, seg4/5=ws2 l0/l1
__global__ __launch_bounds__(256) void wcvt_all(const float* __restrict__ w1,
                                                const float* __restrict__ w2,
                                                const float* __restrict__ ws1,
                                                const float* __restrict__ ws2,
                                                _Float16* __restrict__ wt) {
    int i = blockIdx.x * 256 + threadIdx.x;
    if (i >= 6 * 16384) return;
    int seg = i >> 14;
    int r = i & 16383;
    int j = r >> 7, k = r & 127;
    float val = 0.f;
    switch (seg) {
        case 0: val = w1[k * 128 + j]; break;
        case 1: val = (k < 64) ? w2[k * 128 + j] : 0.f; break;
        case 2: val = ws1[k * 128 + j]; break;
        case 3: val = ws1[16384 + k * 128 + j]; break;
        case 4: val = ws2[k * 128 + j]; break;
        case 5: val = ws2[16384 + k * 128 + j]; break;
    }
    wt[i] = (_Float16)val;
}

// ---------------- conv (batched) ----------------

// MFMA matmul: z = dinv * (xc @ W), K=128 uniform; weight segment selected per tile side.
__global__ __launch_bounds__(256) void matmul_mfma(const _Float16* __restrict__ xc,
                                                   const _Float16* __restrict__ wt1,
                                                   const _Float16* __restrict__ wt2,
                                                   const float* __restrict__ dinv,
                                                   _Float16* __restrict__ outc,
                                                   int N1, int NT) {
    int wid = blockIdx.x * 4 + (threadIdx.x >> 6);
    int lane = threadIdx.x & 63;
    int row16 = lane & 15;
    int oct = lane >> 4;
    int ntiles = NT >> 4;
    if (wid >= ntiles) return;
    int n0 = wid << 4;
    int na = n0 + row16;
    const _Float16* wt = (n0 < N1) ? wt1 : wt2;

    f32x4 acc[8];
#pragma unroll
    for (int ob = 0; ob < 8; ++ob) acc[ob] = (f32x4){0.f, 0.f, 0.f, 0.f};

#pragma unroll
    for (int kb = 0; kb < 128; kb += 32) {
        int ka = kb + oct * 8;
        f16x8 a = *(const f16x8*)(xc + ((size_t)(ka >> 4) * NT + na) * CHK + (ka & (CHK - 1)));
#pragma unroll
        for (int ob = 0; ob < 8; ++ob) {
            int j = ob * 16 + row16;
            f16x8 b = *(const f16x8*)(wt + (size_t)j * 128 + ka);
            acc[ob] = __builtin_amdgcn_mfma_f32_16x16x32_f16(a, b, acc[ob], 0, 0, 0);
        }
    }

#pragma unroll
    for (int r = 0; r < 4; ++r) {
        int n = n0 + oct * 4 + r;
        float dn = dinv[n];
#pragma unroll
        for (int ob = 0; ob < 8; ++ob) {
            outc[((size_t)ob * NT + n) * CHK + row16] = (_Float16)(acc[ob][r] * dn);
        }
    }
}

// Chunk-resident gather, fp16, 4-phase predicated with 4-wide rounds:
// 8 lanes/node = 2 half-row x 4 edge-phase; per round 4 clamped masked loads.
// Round width 4 (was 8) cuts load amplification 1.95x -> 1.4x at mean deg 16
// (mean rounds 1.0 -> 1.45; TLP at ~45% occupancy hides the extra latency).
__global__ __launch_bounds__(256) void gather_chunked(const int* __restrict__ off,
                                                      const unsigned short* __restrict__ csr_src,
                                                      const float* __restrict__ dinv,
                                                      const _Float16* __restrict__ zc,
                                                      const float* __restrict__ b1,
                                                      const float* __restrict__ b2,
                                                      _Float16* __restrict__ outc,
                                                      int N1, int NT) {
    const int c = blockIdx.x;                          // feature chunk = XCD
    const int n = blockIdx.y * 32 + (threadIdx.x >> 3);
    if (n >= NT) return;
    const int sub = threadIdx.x & 7;
    const int h8 = (sub & 1) << 3;                     // half-row: halves 0..7 or 8..15
    const int ph = sub >> 1;                           // edge phase 0..3
    const int sbase = (n < N1) ? 0 : N1;
    const _Float16* base = zc + ((size_t)c * NT + sbase) * CHK + h8;   // indexed by LOCAL s
    const int e0 = off[n], e1 = off[n + 1];
    const int deg = e1 - e0;
    const int cl = (deg > ph) ? ((deg - ph + 3) >> 2) : 0;   // edges this phase covers
    // hoist self row + bias + dinv above the edge loop
    const float dn = dinv[n];
    const f16x8 zs = *(const f16x8*)(base + (size_t)(n - sbase) * CHK);
    const float* bsel = (n < N1) ? b1 : b2;
    const float4 bb0 = *(const float4*)(bsel + c * CHK + h8);
    const float4 bb1 = *(const float4*)(bsel + c * CHK + h8 + 4);

    float a0 = 0.f, a1 = 0.f, a2 = 0.f, a3 = 0.f, a4 = 0.f, a5 = 0.f, a6 = 0.f, a7 = 0.f;
    for (int t = 0; t < cl; t += 4) {
        int slast = e1 - 1;   // valid whenever loop runs (cl>0 -> deg>0)
#pragma unroll
        for (int i = 0; i < 4; ++i) {
            int idx = t + i;
            int ee = e0 + ph + 4 * idx;
            bool valid = idx < cl;
            int epos = valid ? ee : slast;
            int s = csr_src[epos];
            f16x8 v = *(const f16x8*)(base + (size_t)s * CHK);
            float m = valid ? 1.f : 0.f;
            a0 += (float)v[0] * m; a1 += (float)v[1] * m;
            a2 += (float)v[2] * m; a3 += (float)v[3] * m;
            a4 += (float)v[4] * m; a5 += (float)v[5] * m;
            a6 += (float)v[6] * m; a7 += (float)v[7] * m;
        }
    }
    // reduce the 4 phases (lanes sub^2, sub^4 share the same half-row)
    a0 += __shfl_xor(a0, 2); a1 += __shfl_xor(a1, 2); a2 += __shfl_xor(a2, 2); a3 += __shfl_xor(a3, 2);
    a4 += __shfl_xor(a4, 2); a5 += __shfl_xor(a5, 2); a6 += __shfl_xor(a6, 2); a7 += __shfl_xor(a7, 2);
    a0 += __shfl_xor(a0, 4); a1 += __shfl_xor(a1, 4); a2 += __shfl_xor(a2, 4); a3 += __shfl_xor(a3, 4);
    a4 += __shfl_xor(a4, 4); a5 += __shfl_xor(a5, 4); a6 += __shfl_xor(a6, 4); a7 += __shfl_xor(a7, 4);
    if (ph == 0) {
        float o0 = (a0 + (float)zs[0]) * dn + bb0.x;
        float o1 = (a1 + (float)zs[1]) * dn + bb0.y;
        float o2 = (a2 + (float)zs[2]) * dn + bb0.z;
        float o3 = (a3 + (float)zs[3]) * dn + bb0.w;
        float o4 = (a4 + (float)zs[4]) * dn + bb1.x;
        float o5 = (a5 + (float)zs[5]) * dn + bb1.y;
        float o6 = (a6 + (float)zs[6]) * dn + bb1.z;
        float o7 = (a7 + (float)zs[7]) * dn + bb1.w;
        f16x8 o;
        o[0] = (_Float16)(o0 > 0.f ? o0 : 0.f);
        o[1] = (_Float16)(o1 > 0.f ? o1 : 0.f);
        o[2] = (_Float16)(o2 > 0.f ? o2 : 0.f);
        o[3] = (_Float16)(o3 > 0.f ? o3 : 0.f);
        o[4] = (_Float16)(o4 > 0.f ? o4 : 0.f);
        o[5] = (_Float16)(o5 > 0.f ? o5 : 0.f);
        o[6] = (_Float16)(o6 > 0.f ? o6 : 0.f);
        o[7] = (_Float16)(o7 > 0.f ? o7 : 0.f);
        *(f16x8*)(outc + ((size_t)c * NT + n) * CHK + h8) = o;
    }
}

// ---------------- pooling + head (batched) ----------------

__global__ void pool_kernel(const _Float16* __restrict__ h, const int* __restrict__ bnd,
                            float* __restrict__ part, int N1, int NT) {
    int g = blockIdx.x;
    int cch = blockIdx.y;
    int side = blockIdx.z;
    int j = threadIdx.x;   // HD threads
    const int* bn = bnd + side * (NG + 1);
    int nbase = side * N1;
    size_t fo = ((size_t)(j >> 4) * NT) * CHK + (j & (CHK - 1));
    int s = bn[g], e = bn[g + 1];
    float acc = 0.f;
    for (int n = s + cch; n < e; n += PCH) acc += (float)h[fo + (size_t)(nbase + n) * CHK];
    part[(((size_t)side * PCH + cch) * NG + g) * HD + j] = acc;
}

__global__ void lin_kernel(const float* __restrict__ part, const float* __restrict__ cnt,
                           const float* __restrict__ W1, const float* __restrict__ bl1,
                           const float* __restrict__ W2, const float* __restrict__ bl2,
                           float* __restrict__ out) {
    __shared__ float row[HD];
    int g = blockIdx.x, side = blockIdx.y, j = threadIdx.x;
    const float* W = side ? W2 : W1;
    const float* bl = side ? bl2 : bl1;
    float s0 = 0.f;
#pragma unroll
    for (int c = 0; c < PCH; ++c) s0 += part[(((size_t)side * PCH + c) * NG + g) * HD + j];
    float c = cnt[side * NG + g];
    c = c > 1.f ? c : 1.f;
    row[j] = s0 / c;
    __syncthreads();
    float s = bl[j];
#pragma unroll 8
    for (int k = 0; k < HD; ++k) s += row[k] * W[k * HD + j];
    out[(size_t)side * NG * HD + g * HD + j] = s > 0.f ? s : 0.f;
}

__global__ void final_kernel(const float* __restrict__ outg,
                             const float* __restrict__ W3, const float* __restrict__ b3,
                             float* __restrict__ out) {
    __shared__ float c[2 * HD];
    __shared__ float logit[NC];
    __shared__ float lse;
    int g = blockIdx.x, t = threadIdx.x;   // 256 threads
    c[t] = (t < HD) ? outg[g * HD + t] : outg[NG * HD + g * HD + (t - HD)];
    __syncthreads();
    if (t < NC) {
        float s = b3[t];
#pragma unroll 8
        for (int k = 0; k < 2 * HD; ++k) s += c[k] * W3[k * NC + t];
        logit[t] = s;
    }
    __syncthreads();
    if (t == 0) {
        float m = logit[0];
        for (int i = 1; i < NC; ++i) m = fmaxf(m, logit[i]);
        float s = 0.f;
        for (int i = 0; i < NC; ++i) s += expf(logit[i] - m);
        lse = m + logf(s);
    }
    __syncthreads();
    if (t < NC) out[2 * NG * HD + g * NC + t] = logit[t] - lse;
}

// ---------------- host side ----------------

extern "C" void kernel_launch(void* const* d_in, const int* in_sizes, int n_in,
                              void* d_out, int out_size, void* d_ws, size_t ws_size,
                              hipStream_t stream) {
    const float* x1  = (const float*)d_in[0];
    const int*   ei1 = (const int*)d_in[1];
    const int*   b1a = (const int*)d_in[2];
    const float* x2  = (const float*)d_in[3];
    const int*   ei2 = (const int*)d_in[4];
    const int*   b2a = (const int*)d_in[5];
    const float* conv1_w = (const float*)d_in[6];
    const float* conv1_b = (const float*)d_in[7];
    const float* convs1_w = (const float*)d_in[8];
    const float* convs1_b = (const float*)d_in[9];
    const float* conv2_w = (const float*)d_in[10];
    const float* conv2_b = (const float*)d_in[11];
    const float* convs2_w = (const float*)d_in[12];
    const float* convs2_b = (const float*)d_in[13];
    const float* lin1_w = (const float*)d_in[14];
    const float* lin1_b = (const float*)d_in[15];
    const float* lin2_w = (const float*)d_in[16];
    const float* lin2_b = (const float*)d_in[17];
    const float* lin3_w = (const float*)d_in[18];
    const float* lin3_b = (const float*)d_in[19];

    const int N1 = in_sizes[2];
    const int N2 = in_sizes[5];
    const int E1 = in_sizes[1] / 2;
    const int E2 = in_sizes[4] / 2;
    const int NT = N1 + N2;
    const int ET = E1 + E2;
    const int cap = ET / NXCD + 8192;   // per-partition capacity (binomial margin)

    const int* src1 = ei1;
    const int* dst1 = ei1 + E1;
    const int* src2 = ei2;
    const int* dst2 = ei2 + E2;

    char* ws = (char*)d_ws;
    size_t p = 0;
    auto alloc = [&](size_t bytes) { void* r = ws + p; p = (p + bytes + 255) & ~(size_t)255; return r; };
    _Float16* B0  = (_Float16*)alloc((size_t)NT * HD * sizeof(_Float16));
    _Float16* B1  = (_Float16*)alloc((size_t)NT * HD * sizeof(_Float16));
    _Float16* XC  = (_Float16*)alloc((size_t)NT * HD * sizeof(_Float16));
    _Float16* WT  = (_Float16*)alloc((size_t)6 * 16384 * sizeof(_Float16));
    float* dinv   = (float*)alloc((size_t)NT * sizeof(float));
    float* part   = (float*)alloc((size_t)2 * PCH * NG * HD * sizeof(float));
    float* cnt    = (float*)alloc((size_t)2 * NG * sizeof(float));
    int* deg      = (int*)alloc((size_t)NT * sizeof(int));
    int* off      = (int*)alloc((size_t)(NT + 1) * sizeof(int));
    int* cursor   = (int*)alloc((size_t)NT * sizeof(int));
    unsigned short* csr_src = (unsigned short*)alloc((size_t)ET * sizeof(unsigned short));
    int* bsum     = (int*)alloc(512 * sizeof(int));
    int* bnd      = (int*)alloc((size_t)2 * (NG + 1) * sizeof(int));
    int* pcnt     = (int*)alloc((size_t)NXCD * sizeof(int));
    unsigned* pbuf = (unsigned*)alloc((size_t)NXCD * cap * sizeof(unsigned));

    float* out = (float*)d_out;
    const int nb = (NT + 255) / 256;   // 391 <= 512

    // conversions
    wcvt_all<<<(6 * 16384 + 255) / 256, 256, 0, stream>>>(conv1_w, conv2_w, convs1_w, convs2_w, WT);
    xcvt_all<<<(NT * 16 + 255) / 256, 256, 0, stream>>>(x1, x2, XC, N1, NT);

    // edge binning + CSR build (both sides, one node space)
    hipMemsetAsync(pcnt, 0, NXCD * sizeof(int), stream);
    hipMemsetAsync(deg, 0, (size_t)NT * sizeof(int), stream);
    part_x<<<1024, 256, 0, stream>>>(src1, dst1, E1, src2, dst2, E2, N1, NT, cap, pcnt, pbuf);
    hist_p<<<2048, 256, 0, stream>>>(pbuf, pcnt, cap, NT, deg);
    block_sum<<<nb, 256, 0, stream>>>(deg, NT, bsum);
    scan_bsum<<<1, 512, 0, stream>>>(bsum, nb);
    scan_write<<<nb, 256, 0, stream>>>(deg, bsum, NT, ET, off, cursor, dinv);
    fill_p<<<2048, 256, 0, stream>>>(pbuf, pcnt, cap, NT, cursor, csr_src);
    bounds_kernel<<<2, NG, 0, stream>>>(b1a, b2a, N1, bnd, cnt);

    const int mm_blocks = ((NT >> 4) + 3) / 4;
    const dim3 ga_grid(NXCD, (NT + 31) / 32);

    for (int l = 0; l < 3; ++l) {
        const _Float16* in = (l == 0) ? XC : B1;
        const _Float16* wt1 = WT + ((l == 0) ? 0 : (size_t)(2 + (l - 1)) * 16384);
        const _Float16* wt2 = WT + ((l == 0) ? (size_t)16384 : (size_t)(4 + (l - 1)) * 16384);
        const float* bb1 = (l == 0) ? conv1_b : convs1_b + (size_t)(l - 1) * HD;
        const float* bb2 = (l == 0) ? conv2_b : convs2_b + (size_t)(l - 1) * HD;
        matmul_mfma<<<mm_blocks, 256, 0, stream>>>(in, wt1, wt2, dinv, B0, N1, NT);
        gather_chunked<<<ga_grid, 256, 0, stream>>>(off, csr_src, dinv, B0, bb1, bb2, B1, N1, NT);
    }

    pool_kernel<<<dim3(NG, PCH, 2), HD, 0, stream>>>(B1, bnd, part, N1, NT);
    lin_kernel<<<dim3(NG, 2), HD, 0, stream>>>(part, cnt, lin1_w, lin1_b, lin2_w, lin2_b, out);
    final_kernel<<<NG, 2 * HD, 0, stream>>>(out, lin3_w, lin3_b, out);
}